// Round 7
// baseline (589.550 us; speedup 1.0000x reference)
//
#include <hip/hip_runtime.h>

#define NN 100000      // nodes
#define EE 800000      // edges per type
#define TT 3           // edge types
#define D  128         // feature dim
#define LSTRIDE 392    // 3*D + 8 pad (elements)

typedef unsigned short bf16_t;

typedef __bf16 bf16x8_t __attribute__((ext_vector_type(8)));
typedef float  f32x4_t  __attribute__((ext_vector_type(4)));

union ABFrag { bf16x8_t v; ushort u[8]; uint4 q; };

__device__ __forceinline__ bf16_t f2bf(float f) {
    unsigned u = __float_as_uint(f);
    u += 0x7fff + ((u >> 16) & 1);      // round-to-nearest-even
    return (bf16_t)(u >> 16);
}
__device__ __forceinline__ float bf_lo(unsigned p) { return __uint_as_float(p << 16); }
__device__ __forceinline__ float bf_hi(unsigned p) { return __uint_as_float(p & 0xFFFF0000u); }

// ---------------- prep: quant x -> bf16, W -> bf16 transposed, zero deg3 ----------------
#define QBLK 12500             // quant blocks: 12500*256*4 = NN*D exactly
#define WBLK 192               // wconv blocks: 3 types * 64 n-pairs
#define ZBLK 1172              // zero blocks: 1172*256 >= 3*NN
__global__ void prep_kernel(const float* __restrict__ x, const float* __restrict__ W,
                            bf16_t* __restrict__ xq, bf16_t* __restrict__ WT,
                            int* __restrict__ deg3) {
    int blk = blockIdx.x, tid = threadIdx.x;
    if (blk < QBLK) {
        int i = (blk * 256 + tid) * 4;
        float4 f = *(const float4*)(x + i);
        uint2 p;
        p.x = (unsigned)f2bf(f.x) | ((unsigned)f2bf(f.y) << 16);
        p.y = (unsigned)f2bf(f.z) | ((unsigned)f2bf(f.w) << 16);
        *(uint2*)(xq + i) = p;
    } else if (blk < QBLK + WBLK) {
        int bb = blk - QBLK;
        int t = bb >> 6;                         // 0..2
        int n = (bb & 63) * 2 + (tid >> 7);      // 0..127
        int k = tid & 127;
        WT[((size_t)t * D + n) * D + k] = f2bf(W[((size_t)t * D + k) * D + n]);
    } else {
        int i = (blk - QBLK - WBLK) * 256 + tid;
        if (i < 3 * NN) deg3[i] = 0;
    }
}

// ---------------- degree count, MLP=8, no return ----------------
__global__ void deg_kernel(const int* __restrict__ edges, int* __restrict__ deg3) {
    int t = blockIdx.y;
    int e0 = (blockIdx.x * 256 + threadIdx.x) * 8;
    if (e0 >= EE) return;                        // EE % 8 == 0
    const int* dstp = edges + (size_t)t * 2 * EE + EE;
    int4 a = *(const int4*)(dstp + e0);
    int4 c = *(const int4*)(dstp + e0 + 4);
    int* dg = deg3 + t * NN;
    atomicAdd(&dg[a.x], 1); atomicAdd(&dg[a.y], 1);
    atomicAdd(&dg[a.z], 1); atomicAdd(&dg[a.w], 1);
    atomicAdd(&dg[c.x], 1); atomicAdd(&dg[c.y], 1);
    atomicAdd(&dg[c.z], 1); atomicAdd(&dg[c.w], 1);
}

// ---------------- scan1 (+dis): per-block sums of cnt, dis3 written inline ----------------
__global__ void scan1_kernel(const int* __restrict__ deg3, float* __restrict__ dis3,
                             int* __restrict__ bsum) {
    __shared__ int s[256];
    int i = blockIdx.x * 256 + threadIdx.x;
    int c = 0;
    if (i < NN) {
        int d0 = deg3[i], d1 = deg3[NN + i], d2 = deg3[2 * NN + i];
        c = d0 + d1 + d2;
        dis3[i]          = rsqrtf((float)d0 + 1.f);
        dis3[NN + i]     = rsqrtf((float)d1 + 1.f);
        dis3[2 * NN + i] = rsqrtf((float)d2 + 1.f);
    }
    s[threadIdx.x] = c;
    __syncthreads();
    for (int off = 128; off > 0; off >>= 1) {
        if (threadIdx.x < off) s[threadIdx.x] += s[threadIdx.x + off];
        __syncthreads();
    }
    if (threadIdx.x == 0) bsum[blockIdx.x] = s[0];
}

__global__ void scan2_kernel(int* __restrict__ bsum, int nblk) {
    __shared__ int s[512];
    int tid = threadIdx.x;
    s[tid] = (tid < nblk) ? bsum[tid] : 0;
    __syncthreads();
    for (int off = 1; off < 512; off <<= 1) {
        int t = 0;
        if (tid >= off) t = s[tid - off];
        __syncthreads();
        if (tid >= off) s[tid] += t;
        __syncthreads();
    }
    if (tid < nblk) bsum[tid] = (tid == 0) ? 0 : s[tid - 1];  // exclusive
}

__global__ void scan3_kernel(const int* __restrict__ deg3, const int* __restrict__ bsum,
                             int* __restrict__ offs3, int* __restrict__ cursor3) {
    __shared__ int s[256];
    int i = blockIdx.x * 256 + threadIdx.x;
    int d0 = 0, d1 = 0, v = 0;
    if (i < NN) {
        d0 = deg3[i]; d1 = deg3[NN + i];
        v = d0 + d1 + deg3[2 * NN + i];
    }
    s[threadIdx.x] = v;
    __syncthreads();
    for (int off = 1; off < 256; off <<= 1) {
        int t = 0;
        if (threadIdx.x >= off) t = s[threadIdx.x - off];
        __syncthreads();
        if (threadIdx.x >= off) s[threadIdx.x] += t;
        __syncthreads();
    }
    if (i < NN) {
        int o = bsum[blockIdx.x] + s[threadIdx.x] - v;  // exclusive
        offs3[i]          = o;          cursor3[i]          = o;
        offs3[NN + i]     = o + d0;     cursor3[NN + i]     = o + d0;
        offs3[2 * NN + i] = o + d0 + d1; cursor3[2 * NN + i] = o + d0 + d1;
    }
}

// ---------------- fill: cursor-atomic CSR, 4B records (src only), MLP=8 ----------------
__global__ void fill_kernel(const int* __restrict__ edges, int* __restrict__ cursor3,
                            int* __restrict__ recs) {
    int t = blockIdx.y;
    int e0 = (blockIdx.x * 256 + threadIdx.x) * 8;
    if (e0 >= EE) return;
    const int* base = edges + (size_t)t * 2 * EE;
    int4 sa = *(const int4*)(base + e0);
    int4 sb = *(const int4*)(base + e0 + 4);
    int4 da = *(const int4*)(base + EE + e0);
    int4 db = *(const int4*)(base + EE + e0 + 4);
    int* cur = cursor3 + t * NN;
    recs[atomicAdd(&cur[da.x], 1)] = sa.x;
    recs[atomicAdd(&cur[da.y], 1)] = sa.y;
    recs[atomicAdd(&cur[da.z], 1)] = sa.z;
    recs[atomicAdd(&cur[da.w], 1)] = sa.w;
    recs[atomicAdd(&cur[db.x], 1)] = sb.x;
    recs[atomicAdd(&cur[db.y], 1)] = sb.y;
    recs[atomicAdd(&cur[db.z], 1)] = sb.z;
    recs[atomicAdd(&cur[db.w], 1)] = sb.w;
}

// ---------------- fused: wave-per-node, 3 concurrent MLP streams + MFMA ----------------
// Phase 1: one 64-rec window covers the node's combined (t0,t1,t2) segment; each round
// issues 4 clamp-padded row loads per live stream (12 in flight), FMA into per-type accs.
// Phase 2: waves 0..7 compute out[16x128] = sum_t Y_t @ W_t + bias via MFMA 16x16x32.
#define STREAM_LOAD(S, BEG, LAST, DBASE, DV)                                   \
    if (r < nb##S) {                                                           \
        _Pragma("unroll")                                                      \
        for (int k = 0; k < 4; ++k) {                                          \
            int j = (BEG) + r * 4 + k;                                         \
            int jj = j < (LAST) ? j : (LAST);                                  \
            int sidx = __builtin_amdgcn_readlane(rl, jj);                      \
            u[(S) * 4 + k] = *(const unsigned*)(xq + (size_t)sidx * D + lane * 2); \
            float ws = dis3[(DBASE) + sidx];                                   \
            w[(S) * 4 + k] = (j <= (LAST)) ? ws * (DV) : 0.f;                  \
        }                                                                      \
    }
#define STREAM_FMA(S, A0, A1)                                                  \
    if (r < nb##S) {                                                           \
        _Pragma("unroll")                                                      \
        for (int k = 0; k < 4; ++k) {                                          \
            A0 += w[(S) * 4 + k] * bf_lo(u[(S) * 4 + k]);                      \
            A1 += w[(S) * 4 + k] * bf_hi(u[(S) * 4 + k]);                      \
        }                                                                      \
    }
#define SLOW_T(ST, CNT, DBASE, DV, A0, A1)                                     \
    { int st = (ST), c = (CNT);                                                \
      for (int bj = 0; bj < c; bj += 64) {                                     \
          int m = c - bj; if (m > 64) m = 64;                                  \
          int rl2 = recs[st + bj + (lane < m ? lane : m - 1)];                 \
          for (int j = 0; j < m; ++j) {                                        \
              int sidx = __builtin_amdgcn_readlane(rl2, j);                    \
              unsigned uu = *(const unsigned*)(xq + (size_t)sidx * D + lane * 2); \
              float wv = dis3[(DBASE) + sidx] * (DV);                          \
              A0 += wv * bf_lo(uu); A1 += wv * bf_hi(uu);                      \
          } } }

__global__ __launch_bounds__(1024, 8) void fused_kernel(const bf16_t* __restrict__ xq,
                                                        const float* __restrict__ dis3,
                                                        const int* __restrict__ offs3,
                                                        const int* __restrict__ deg3,
                                                        const int* __restrict__ recs,
                                                        const bf16_t* __restrict__ WT,
                                                        const float* __restrict__ b,
                                                        float* __restrict__ out) {
    __shared__ ushort ylds[16 * LSTRIDE];
    int tid  = threadIdx.x;
    int lane = tid & 63;
    int wave = tid >> 6;            // 0..15 = local node index
    int n0 = blockIdx.x * 16;       // NN % 16 == 0
    int n  = n0 + wave;

    int d0 = deg3[n], d1 = deg3[NN + n], d2 = deg3[2 * NN + n];
    int s0 = offs3[n];
    float dv0 = dis3[n], dv1 = dis3[NN + n], dv2 = dis3[2 * NN + n];

    unsigned su = *(const unsigned*)(xq + (size_t)n * D + lane * 2);
    float xs0 = bf_lo(su), xs1 = bf_hi(su);
    float a00 = dv0 * dv0 * xs0, a01 = dv0 * dv0 * xs1;   // self-loop terms
    float a10 = dv1 * dv1 * xs0, a11 = dv1 * dv1 * xs1;
    float a20 = dv2 * dv2 * xs0, a21 = dv2 * dv2 * xs1;

    int cnt = d0 + d1 + d2;
    if (cnt > 0 && cnt <= 64) {
        int rl = recs[s0 + (lane < cnt ? lane : cnt - 1)];   // record window in registers
        int beg1 = d0, beg2 = d0 + d1;
        int last0 = d0 - 1, last1 = beg2 - 1, last2 = cnt - 1;
        int nb0 = (d0 + 3) >> 2, nb1 = (d1 + 3) >> 2, nb2 = (d2 + 3) >> 2;
        int rounds = nb0 > nb1 ? nb0 : nb1; if (nb2 > rounds) rounds = nb2;
        for (int r = 0; r < rounds; ++r) {
            unsigned u[12]; float w[12];
            STREAM_LOAD(0, 0,    last0, 0,      dv0)
            STREAM_LOAD(1, beg1, last1, NN,     dv1)
            STREAM_LOAD(2, beg2, last2, 2 * NN, dv2)
            STREAM_FMA(0, a00, a01)
            STREAM_FMA(1, a10, a11)
            STREAM_FMA(2, a20, a21)
        }
    } else if (cnt > 64) {
        SLOW_T(s0,           d0, 0,      dv0, a00, a01)
        SLOW_T(s0 + d0,      d1, NN,     dv1, a10, a11)
        SLOW_T(s0 + d0 + d1, d2, 2 * NN, dv2, a20, a21)
    }

    *(unsigned*)(ylds + wave * LSTRIDE + 0 * D + lane * 2) =
        (unsigned)f2bf(a00) | ((unsigned)f2bf(a01) << 16);
    *(unsigned*)(ylds + wave * LSTRIDE + 1 * D + lane * 2) =
        (unsigned)f2bf(a10) | ((unsigned)f2bf(a11) << 16);
    *(unsigned*)(ylds + wave * LSTRIDE + 2 * D + lane * 2) =
        (unsigned)f2bf(a20) | ((unsigned)f2bf(a21) << 16);
    __syncthreads();

    // ---- phase 2: 8 active waves, wave w -> column block w ----
    if (wave < 8) {
        int quad = lane >> 4;
        int lid  = lane & 15;
        int col  = wave * 16 + lid;

        ABFrag a[12];   // A[m=lid][k = t*128 + s*32 + quad*8 + j]
#pragma unroll
        for (int t = 0; t < TT; ++t)
#pragma unroll
            for (int s = 0; s < 4; ++s)
                a[t * 4 + s].q = *(const uint4*)(ylds + lid * LSTRIDE + t * D + s * 32 + quad * 8);

        f32x4_t acc = {0.f, 0.f, 0.f, 0.f};
#pragma unroll
        for (int t = 0; t < TT; ++t) {
            const bf16_t* wn = WT + ((size_t)t * D + col) * D;   // B[n=col][k]
#pragma unroll
            for (int s = 0; s < 4; ++s) {
                ABFrag bfr;
                bfr.q = *(const uint4*)(wn + s * 32 + quad * 8);
                acc = __builtin_amdgcn_mfma_f32_16x16x32_bf16(a[t * 4 + s].v, bfr.v, acc, 0, 0, 0);
            }
        }
        float bc = b[col] + b[D + col] + b[2 * D + col];
#pragma unroll
        for (int r = 0; r < 4; ++r)
            out[(size_t)(n0 + quad * 4 + r) * D + col] = acc[r] + bc;  // C/D: row=quad*4+reg
    }
}

extern "C" void kernel_launch(void* const* d_in, const int* in_sizes, int n_in,
                              void* d_out, int out_size, void* d_ws, size_t ws_size,
                              hipStream_t stream) {
    const float* x     = (const float*)d_in[0];   // [NN, D]
    const int*   edges = (const int*)d_in[1];     // [TT, 2, EE]
    const float* W     = (const float*)d_in[2];   // [TT, D, D]
    const float* b     = (const float*)d_in[3];   // [TT, D]
    float*       out   = (float*)d_out;           // [NN, D]

    // workspace layout (~40 MB total)
    char* w = (char*)d_ws;
    bf16_t* xq      = (bf16_t*)w;                                 // NN*D bf16 = 25.6 MB
    float*  dis3    = (float*)(w + (size_t)NN * D * 2);           // 3*NN f32
    int*    deg3    = (int*)((char*)dis3 + (size_t)3 * NN * 4);   // 3*NN
    int*    offs3   = deg3 + 3 * NN;                              // 3*NN
    int*    cursor3 = offs3 + 3 * NN;                             // 3*NN
    int*    bsum    = cursor3 + 3 * NN;                           // 512
    int*    recs    = bsum + 512;                                 // 3*EE = 9.6 MB
    bf16_t* WT      = (bf16_t*)(recs + (size_t)3 * EE);           // 3*D*D bf16 = 96 KB

    const int nblk = (NN + 255) / 256;  // 391

    // 0) prep: quant + wconv + zero deg3 (one kernel)
    prep_kernel<<<QBLK + WBLK + ZBLK, 256, 0, stream>>>(x, W, xq, WT, deg3);

    // 1) degree count
    {
        dim3 g((EE / 8 + 255) / 256, TT);
        deg_kernel<<<g, 256, 0, stream>>>(edges, deg3);
    }

    // 2) scan (dis fused into scan1) -> offs3, cursor3
    scan1_kernel<<<nblk, 256, 0, stream>>>(deg3, dis3, bsum);
    scan2_kernel<<<1, 512, 0, stream>>>(bsum, nblk);
    scan3_kernel<<<nblk, 256, 0, stream>>>(deg3, bsum, offs3, cursor3);

    // 3) fill CSR records (src-only 4B, cursor atomics)
    {
        dim3 g((EE / 8 + 255) / 256, TT);
        fill_kernel<<<g, 256, 0, stream>>>(edges, cursor3, recs);
    }

    // 4) fused 3-stream aggregate + MFMA transform + bias -> out
    fused_kernel<<<NN / 16, 1024, 0, stream>>>(xq, dis3, offs3, deg3, recs, WT, b, out);
}